// Round 3
// baseline (785.074 us; speedup 1.0000x reference)
//
#include <hip/hip_runtime.h>

// ArcMarginProduct: out[b,c] = S * (c==label[b] ? phi : cos)
//   cos = <input_b/||input_b||, weight_c/||weight_c||>
//   phi = cos*cos(m) - sine*sin(m), fallback cos - S*sin(m)*m if cos <= cos(pi-m)
// B=1024, D=512, C=100000. fp32 in/out; bf16 MFMA inside.
//
// R1/R2: prenorm W to bf16 (FETCH 804->55 MB, VALU 36->20%), XCD swizzle.
// R3: global_load_lds(16B) staging into subtiled LDS (m151: +35% at this exact
//     structure), bank-even [kq][16r][8e] subtiles for both stage-writes and
//     ds_read_b128 frag reads, plain stores (nt inflated WRITE 413->552 MB).

#define MDIM 1024
#define KDIM 512
#define NCLS 100000

#define BM 128
#define BN 128
#define BK 32
#define LDST 40   // fallback kernel only: padded row stride

#define NTILES ((NCLS + BN - 1) / BN)   // 782
#define NWG (8 * NTILES)                // 6256, divisible by 8

typedef unsigned short u16;
typedef unsigned int u32;
typedef short s16x8 __attribute__((ext_vector_type(8)));
typedef float f32x4 __attribute__((ext_vector_type(4)));

// round-to-nearest-even fp32 -> bf16, two values packed into a u32
__device__ __forceinline__ u32 pk2(float a, float b) {
  u32 ua = __builtin_bit_cast(u32, a);
  u32 ub = __builtin_bit_cast(u32, b);
  ua += 0x7FFFu + ((ua >> 16) & 1u);
  ub += 0x7FFFu + ((ub >> 16) & 1u);
  return (ua >> 16) | (ub & 0xFFFF0000u);
}

// async global->LDS, 16 B per lane. LDS dest must be wave-uniform base;
// lane l writes base + l*16 B. Global src is per-lane.
__device__ __forceinline__ void gl16(const u16* g, u16* l) {
  __builtin_amdgcn_global_load_lds(
      (const __attribute__((address_space(1))) void*)g,
      (__attribute__((address_space(3))) void*)l, 16, 0, 0);
}

// ---- Kernel 1: L2-normalize input rows, store bf16 row-major [1024][512] ----
__global__ __launch_bounds__(256) void norm_input_kernel(const float* __restrict__ in,
                                                         u16* __restrict__ abf) {
  const int row = blockIdx.x;
  const int tid = threadIdx.x;
  const float2 v = *reinterpret_cast<const float2*>(in + (size_t)row * KDIM + 2 * tid);
  float ss = v.x * v.x + v.y * v.y;
#pragma unroll
  for (int off = 32; off > 0; off >>= 1) ss += __shfl_down(ss, off);
  __shared__ float part[4];
  if ((tid & 63) == 0) part[tid >> 6] = ss;
  __syncthreads();
  const float tot = part[0] + part[1] + part[2] + part[3];
  const float rn = 1.0f / fmaxf(sqrtf(tot), 1e-12f);  // F.normalize: x / max(||x||, eps)
  reinterpret_cast<u32*>(abf)[row * (KDIM / 2) + tid] = pk2(v.x * rn, v.y * rn);
}

// ---- Kernel 1b: L2-normalize weight rows, store bf16 row-major [100000][512] ----
// One wave per row, 4 rows per block. 204.8 MB read + 102.4 MB write, pure streaming.
__global__ __launch_bounds__(256) void norm_weight_kernel(const float* __restrict__ W,
                                                          u16* __restrict__ wbf) {
  const int row = blockIdx.x * 4 + (threadIdx.x >> 6);
  const int lane = threadIdx.x & 63;
  const float* p = W + (size_t)row * KDIM + lane * 8;
  const float4 v0 = *reinterpret_cast<const float4*>(p);
  const float4 v1 = *reinterpret_cast<const float4*>(p + 4);
  float ss = v0.x * v0.x + v0.y * v0.y + v0.z * v0.z + v0.w * v0.w
           + v1.x * v1.x + v1.y * v1.y + v1.z * v1.z + v1.w * v1.w;
#pragma unroll
  for (int off = 32; off > 0; off >>= 1) ss += __shfl_xor(ss, off);
  const float rn = 1.0f / fmaxf(sqrtf(ss), 1e-12f);
  uint4 o;
  o.x = pk2(v0.x * rn, v0.y * rn);
  o.y = pk2(v0.z * rn, v0.w * rn);
  o.z = pk2(v1.x * rn, v1.y * rn);
  o.w = pk2(v1.z * rn, v1.w * rn);
  *reinterpret_cast<uint4*>(wbf + (size_t)row * KDIM + lane * 8) = o;
}

// ---- Kernel 2 (main): C = Anorm * Wnorm^T, both bf16, fused ArcFace epilogue ----
// 128x128 tile, 256 threads = 4 waves 2x2, each wave 64x64 via 4x4 of 16x16x32 MFMA.
// LDS layout: per 16-row x 32-k subtile (1 KB): addr = sub*1024B + kq*256B + r*16B.
//   - staged by one gl16 wave-instr per subtile: lane l sources global
//     (row = 16*sub + (l&15), k8 = (l>>4)*8)  ->  LDS base + l*16B  (linear dest)
//   - ds_read_b128 frag (row=16*sub+ln, kq): banks spread evenly (vs 8-bank
//     clustering of the 64B-row layout that caused 2.56e7 conflicts)
// Grid: 1D, bijective XCD swizzle, M fastest within an XCD.
__global__ __launch_bounds__(256) void arcface_gemm_bf16(const u16* __restrict__ Abf,
                                                         const u16* __restrict__ Wbf,
                                                         const int* __restrict__ label,
                                                         float* __restrict__ out) {
  __shared__ u16 lA[BM * BK];   // 8 KB, 8 subtiles
  __shared__ u16 lW[BN * BK];   // 8 KB, 8 subtiles
  __shared__ int lbl[BM];

  const int tid = threadIdx.x;
  const int orig = blockIdx.x;
  const int wg = (orig & 7) * NTILES + (orig >> 3);
  const int m0 = (wg & 7) * BM;
  const int n0 = (wg >> 3) * BN;

  if (tid < BM) lbl[tid] = label[m0 + tid];

  const int lane = tid & 63;
  const int wv = tid >> 6;

  // staging source assignment: lane l -> (row in subtile = l&15, k-slice = l>>4)
  const int sr = lane & 15;
  const int sc = (lane >> 4) * 8;   // elem offset of the 16B chunk
  const u16* aG0 = Abf + (size_t)(m0 + 16 * wv + sr) * KDIM + sc;   // subtile wv
  const u16* aG1 = aG0 + (size_t)64 * KDIM;                          // subtile wv+4
  int wr0 = n0 + 16 * wv + sr;       if (wr0 >= NCLS) wr0 = NCLS - 1;
  int wr1 = n0 + 64 + 16 * wv + sr;  if (wr1 >= NCLS) wr1 = NCLS - 1;
  const u16* wG0 = Wbf + (size_t)wr0 * KDIM + sc;
  const u16* wG1 = Wbf + (size_t)wr1 * KDIM + sc;
  u16* const lA0 = &lA[wv * 512];        // wave-uniform LDS bases (512 elems = 1 KB)
  u16* const lA1 = &lA[(4 + wv) * 512];
  u16* const lW0 = &lW[wv * 512];
  u16* const lW1 = &lW[(4 + wv) * 512];

  f32x4 acc[4][4] = {};

  const int wm = (wv & 1) * 64;
  const int wn = (wv >> 1) * 64;
  const int ln = lane & 15;   // MFMA frag: row within 16-row group
  const int kq = lane >> 4;   // k-slice quad
  const int sA = wm >> 4;     // A subtile base index for this wave
  const int sW = wn >> 4;

  // prologue: stage K-chunk 0
  gl16(aG0, lA0); gl16(aG1, lA1); gl16(wG0, lW0); gl16(wG1, lW1);

  for (int kt = 0; kt < KDIM / BK; ++kt) {
    __syncthreads();   // vmcnt(0) drain: LDS(kt) filled; prev iter's reads done

    // fragment loads: subtiled addressing
    s16x8 af[4], wf[4];
#pragma unroll
    for (int i = 0; i < 4; ++i)
      af[i] = *(const s16x8*)&lA[(sA + i) * 512 + kq * 128 + ln * 8];
#pragma unroll
    for (int j = 0; j < 4; ++j)
      wf[j] = *(const s16x8*)&lW[(sW + j) * 512 + kq * 128 + ln * 8];

    __syncthreads();   // all waves' frag reads retired -> safe to overwrite LDS

    if (kt < KDIM / BK - 1) {   // stage kt+1; loads fly under the MFMA block
      const int o = (kt + 1) * BK;
      gl16(aG0 + o, lA0); gl16(aG1 + o, lA1);
      gl16(wG0 + o, lW0); gl16(wG1 + o, lW1);
    }

#pragma unroll
    for (int i = 0; i < 4; ++i)
#pragma unroll
      for (int j = 0; j < 4; ++j)
        acc[i][j] = __builtin_amdgcn_mfma_f32_16x16x32_bf16(af[i], wf[j], acc[i][j], 0, 0, 0);
  }

  // epilogue: C/D layout col = lane&15, row = (lane>>4)*4 + reg  [verified m89/m91]
  constexpr float S_ = 30.0f;
  constexpr float COS_M = 0.87758256189037276f;
  constexpr float SIN_M = 0.47942553860420301f;
  constexpr float TH_ = -0.87758256189037276f;       // cos(pi - 0.5)
  constexpr float FALLB = 30.0f * 0.47942553860420301f * 0.5f;  // S*sin(m)*m

#pragma unroll
  for (int i = 0; i < 4; ++i) {
    const int lrow_b = wm + 16 * i + 4 * kq;
#pragma unroll
    for (int j = 0; j < 4; ++j) {
      const int col = wn + 16 * j + ln;
      const int gcol = n0 + col;
      if (gcol < NCLS) {
#pragma unroll
        for (int rg = 0; rg < 4; ++rg) {
          const int lrow = lrow_b + rg;
          const float cosv = acc[i][j][rg];
          float o = S_ * cosv;
          if (gcol == lbl[lrow]) {
            const float s2 = fmaxf(1.0f - cosv * cosv, 0.0f);
            const float sine = sqrtf(s2);
            float phi = cosv * COS_M - sine * SIN_M;
            phi = (cosv > TH_) ? phi : (cosv - FALLB);
            o = S_ * phi;
          }
          out[(size_t)(m0 + lrow) * NCLS + gcol] = o;
        }
      }
    }
  }
}

// ---- Fallback kernel (ws too small for bf16 W): previous proven fused version ----
__global__ __launch_bounds__(256) void arcface_gemm(const u16* __restrict__ Abf,
                                                    const float* __restrict__ W,
                                                    const int* __restrict__ label,
                                                    float* __restrict__ out) {
  __shared__ u16 lA[BM * LDST];
  __shared__ u16 lW[BN * LDST];
  __shared__ float rnw[BN];
  __shared__ int lbl[BM];

  const int tid = threadIdx.x;
  const int m0 = blockIdx.x * BM;
  const int n0 = blockIdx.y * BN;

  if (tid < BM) lbl[tid] = label[m0 + tid];

  const int r = tid >> 1;
  const int half = tid & 1;
  int c = n0 + r;
  if (c >= NCLS) c = NCLS - 1;

  const u16* aptr = Abf + (size_t)(m0 + r) * KDIM + half * 16;
  const float* wptr = W + (size_t)c * KDIM + half * 16;

  uint4 a0 = *(const uint4*)(aptr);
  uint4 a1 = *(const uint4*)(aptr + 8);
  float4 w0 = *(const float4*)(wptr);
  float4 w1 = *(const float4*)(wptr + 4);
  float4 w2 = *(const float4*)(wptr + 8);
  float4 w3 = *(const float4*)(wptr + 12);

  f32x4 acc[4][4] = {};
  float ss = 0.0f;

  const int lane = tid & 63;
  const int wv = tid >> 6;
  const int wm = (wv & 1) * 64;
  const int wn = (wv >> 1) * 64;
  const int ln = lane & 15;
  const int kq = lane >> 4;

  const int aw = r * LDST + half * 16;

  for (int kt = 0; kt < KDIM / BK; ++kt) {
    __syncthreads();
    *(uint4*)&lA[aw] = a0;
    *(uint4*)&lA[aw + 8] = a1;
    ss += w0.x * w0.x + w0.y * w0.y + w0.z * w0.z + w0.w * w0.w;
    ss += w1.x * w1.x + w1.y * w1.y + w1.z * w1.z + w1.w * w1.w;
    ss += w2.x * w2.x + w2.y * w2.y + w2.z * w2.z + w2.w * w2.w;
    ss += w3.x * w3.x + w3.y * w3.y + w3.z * w3.z + w3.w * w3.w;
    uint4 p0, p1;
    p0.x = pk2(w0.x, w0.y); p0.y = pk2(w0.z, w0.w);
    p0.z = pk2(w1.x, w1.y); p0.w = pk2(w1.z, w1.w);
    p1.x = pk2(w2.x, w2.y); p1.y = pk2(w2.z, w2.w);
    p1.z = pk2(w3.x, w3.y); p1.w = pk2(w3.z, w3.w);
    *(uint4*)&lW[aw] = p0;
    *(uint4*)&lW[aw + 8] = p1;
    __syncthreads();

    if (kt < KDIM / BK - 1) {
      const u16* ap = aptr + (kt + 1) * BK;
      a0 = *(const uint4*)(ap);
      a1 = *(const uint4*)(ap + 8);
      const float* wp = wptr + (kt + 1) * BK;
      w0 = *(const float4*)(wp);
      w1 = *(const float4*)(wp + 4);
      w2 = *(const float4*)(wp + 8);
      w3 = *(const float4*)(wp + 12);
    }

    s16x8 af[4], wf[4];
#pragma unroll
    for (int i = 0; i < 4; ++i)
      af[i] = *(const s16x8*)&lA[(wm + 16 * i + ln) * LDST + kq * 8];
#pragma unroll
    for (int j = 0; j < 4; ++j)
      wf[j] = *(const s16x8*)&lW[(wn + 16 * j + ln) * LDST + kq * 8];
#pragma unroll
    for (int i = 0; i < 4; ++i)
#pragma unroll
      for (int j = 0; j < 4; ++j)
        acc[i][j] = __builtin_amdgcn_mfma_f32_16x16x32_bf16(af[i], wf[j], acc[i][j], 0, 0, 0);
  }

  const float sst = ss + __shfl_xor(ss, 1);
  if (half == 0) rnw[r] = 1.0f / fmaxf(sqrtf(sst), 1e-12f);
  __syncthreads();

  constexpr float S_ = 30.0f;
  constexpr float COS_M = 0.87758256189037276f;
  constexpr float SIN_M = 0.47942553860420301f;
  constexpr float TH_ = -0.87758256189037276f;
  constexpr float FALLB = 30.0f * 0.47942553860420301f * 0.5f;

#pragma unroll
  for (int i = 0; i < 4; ++i) {
    const int lrow_b = wm + 16 * i + 4 * kq;
#pragma unroll
    for (int j = 0; j < 4; ++j) {
      const int col = wn + 16 * j + ln;
      const int gcol = n0 + col;
      const float rw = rnw[col];
      if (gcol < NCLS) {
#pragma unroll
        for (int rg = 0; rg < 4; ++rg) {
          const int lrow = lrow_b + rg;
          const float cosv = acc[i][j][rg] * rw;
          float o = S_ * cosv;
          if (gcol == lbl[lrow]) {
            const float s2 = fmaxf(1.0f - cosv * cosv, 0.0f);
            const float sine = sqrtf(s2);
            float phi = cosv * COS_M - sine * SIN_M;
            phi = (cosv > TH_) ? phi : (cosv - FALLB);
            o = S_ * phi;
          }
          out[(size_t)(m0 + lrow) * NCLS + gcol] = o;
        }
      }
    }
  }
}

extern "C" void kernel_launch(void* const* d_in, const int* in_sizes, int n_in,
                              void* d_out, int out_size, void* d_ws, size_t ws_size,
                              hipStream_t stream) {
  const float* input = (const float*)d_in[0];
  const int* label = (const int*)d_in[1];
  const float* weight = (const float*)d_in[2];
  float* out = (float*)d_out;
  u16* abf = (u16*)d_ws;  // 1024*512 bf16 = 1 MB normalized input

  hipLaunchKernelGGL(norm_input_kernel, dim3(MDIM), dim3(256), 0, stream, input, abf);

  const size_t a_bytes = (size_t)MDIM * KDIM * sizeof(u16);
  const size_t w_bytes = (size_t)NCLS * KDIM * sizeof(u16);
  if (ws_size >= a_bytes + w_bytes) {
    u16* wbf = abf + (size_t)MDIM * KDIM;  // 100000*512 bf16 = 102.4 MB
    hipLaunchKernelGGL(norm_weight_kernel, dim3(NCLS / 4), dim3(256), 0, stream, weight, wbf);
    hipLaunchKernelGGL(arcface_gemm_bf16, dim3(NWG), dim3(256), 0, stream, abf, wbf, label, out);
  } else {
    dim3 grid(MDIM / BM, (NCLS + BN - 1) / BN);
    hipLaunchKernelGGL(arcface_gemm, grid, dim3(256), 0, stream, abf, weight, label, out);
  }
}

// Round 5
// 781.640 us; speedup vs baseline: 1.0044x; 1.0044x over previous
//
#include <hip/hip_runtime.h>

// ArcMarginProduct: out[b,c] = S * (c==label[b] ? phi : cos)
//   cos = <input_b/||input_b||, weight_c/||weight_c||>
//   phi = cos*cos(m) - sine*sin(m), fallback cos - S*sin(m)*m if cos <= cos(pi-m)
// B=1024, D=512, C=100000. fp32 in/out; bf16 MFMA inside.
//
// R1/R2: prenorm W to bf16 (FETCH 804->55 MB), XCD swizzle, 286 us gemm.
// R3: gl16 subtiled staging -> bank conflicts 2.56e7 -> 0, but 2-barrier
//     full-drain loop stalled on L2 latency (315 us, latency-bound).
// R4: T3+T4 pipeline — triple-buffered LDS, 2-ahead prefetch, ONE raw barrier
//     per K-step with counted s_waitcnt vmcnt(4) (never drain to 0 in-loop),
//     sched_barrier(0) fence, setprio(1) around MFMA cluster (T5).
// R5: resubmit of R4 — container failed twice (infra), kernel never ran.
//     Hazard audit re-done: barrier counts converge, vmcnt ledger sound,
//     addresses in bounds, per-iter asm memory clobber blocks ds_read CSE.

#define MDIM 1024
#define KDIM 512
#define NCLS 100000

#define BM 128
#define BN 128
#define BK 32
#define LDST 40   // fallback kernel only: padded row stride

#define NTILES ((NCLS + BN - 1) / BN)   // 782
#define NWG (8 * NTILES)                // 6256, divisible by 8

typedef unsigned short u16;
typedef unsigned int u32;
typedef short s16x8 __attribute__((ext_vector_type(8)));
typedef float f32x4 __attribute__((ext_vector_type(4)));

// round-to-nearest-even fp32 -> bf16, two values packed into a u32
__device__ __forceinline__ u32 pk2(float a, float b) {
  u32 ua = __builtin_bit_cast(u32, a);
  u32 ub = __builtin_bit_cast(u32, b);
  ua += 0x7FFFu + ((ua >> 16) & 1u);
  ub += 0x7FFFu + ((ub >> 16) & 1u);
  return (ua >> 16) | (ub & 0xFFFF0000u);
}

// async global->LDS, 16 B per lane. LDS dest is wave-uniform base;
// lane l writes base + l*16 B. Global src is per-lane.
__device__ __forceinline__ void gl16(const u16* g, u16* l) {
  __builtin_amdgcn_global_load_lds(
      (const __attribute__((address_space(1))) void*)g,
      (__attribute__((address_space(3))) void*)l, 16, 0, 0);
}

// ---- Kernel 1: L2-normalize input rows, store bf16 row-major [1024][512] ----
__global__ __launch_bounds__(256) void norm_input_kernel(const float* __restrict__ in,
                                                         u16* __restrict__ abf) {
  const int row = blockIdx.x;
  const int tid = threadIdx.x;
  const float2 v = *reinterpret_cast<const float2*>(in + (size_t)row * KDIM + 2 * tid);
  float ss = v.x * v.x + v.y * v.y;
#pragma unroll
  for (int off = 32; off > 0; off >>= 1) ss += __shfl_down(ss, off);
  __shared__ float part[4];
  if ((tid & 63) == 0) part[tid >> 6] = ss;
  __syncthreads();
  const float tot = part[0] + part[1] + part[2] + part[3];
  const float rn = 1.0f / fmaxf(sqrtf(tot), 1e-12f);  // F.normalize: x / max(||x||, eps)
  reinterpret_cast<u32*>(abf)[row * (KDIM / 2) + tid] = pk2(v.x * rn, v.y * rn);
}

// ---- Kernel 1b: L2-normalize weight rows, store bf16 row-major [100000][512] ----
__global__ __launch_bounds__(256) void norm_weight_kernel(const float* __restrict__ W,
                                                          u16* __restrict__ wbf) {
  const int row = blockIdx.x * 4 + (threadIdx.x >> 6);
  const int lane = threadIdx.x & 63;
  const float* p = W + (size_t)row * KDIM + lane * 8;
  const float4 v0 = *reinterpret_cast<const float4*>(p);
  const float4 v1 = *reinterpret_cast<const float4*>(p + 4);
  float ss = v0.x * v0.x + v0.y * v0.y + v0.z * v0.z + v0.w * v0.w
           + v1.x * v1.x + v1.y * v1.y + v1.z * v1.z + v1.w * v1.w;
#pragma unroll
  for (int off = 32; off > 0; off >>= 1) ss += __shfl_xor(ss, off);
  const float rn = 1.0f / fmaxf(sqrtf(ss), 1e-12f);
  uint4 o;
  o.x = pk2(v0.x * rn, v0.y * rn);
  o.y = pk2(v0.z * rn, v0.w * rn);
  o.z = pk2(v1.x * rn, v1.y * rn);
  o.w = pk2(v1.z * rn, v1.w * rn);
  *reinterpret_cast<uint4*>(wbf + (size_t)row * KDIM + lane * 8) = o;
}

// ---- Kernel 2 (main): C = Anorm * Wnorm^T, both bf16, fused ArcFace epilogue ----
// 128x128 tile, 256 threads = 4 waves 2x2, each wave 64x64 via 4x4 of 16x16x32 MFMA.
// LDS: 3 buffers, each [16-row x 32-k subtile]=1KB granules (conflict-free, R3).
// Pipeline (T3+T4): stage(kt+2) issued at iter kt; ONE s_barrier per iter with
// per-wave s_waitcnt vmcnt(4) (oldest stage done, newest stays in flight).
//   RAW: barrier after all waves' vmcnt(4) => buf[kt%3] fully written.
//   WAR: stage(kt+2) hits buf[(kt-1)%3]; issued after barrier(kt), which each
//        wave reaches only after its iter-(kt-1) frag reads retired (lgkmcnt(0)
//        at top of iter kt drains them).
__global__ __launch_bounds__(256) void arcface_gemm_bf16(const u16* __restrict__ Abf,
                                                         const u16* __restrict__ Wbf,
                                                         const int* __restrict__ label,
                                                         float* __restrict__ out) {
  __shared__ u16 lA[3][BM * BK];   // 3 x 8 KB
  __shared__ u16 lW[3][BN * BK];   // 3 x 8 KB
  __shared__ int lbl[BM];

  const int tid = threadIdx.x;
  const int orig = blockIdx.x;
  const int wg = (orig & 7) * NTILES + (orig >> 3);
  const int m0 = (wg & 7) * BM;
  const int n0 = (wg >> 3) * BN;

  if (tid < BM) lbl[tid] = label[m0 + tid];

  const int lane = tid & 63;
  const int wv = tid >> 6;

  // staging source: lane l -> (row in subtile = l&15, 16B k-slice = l>>4)
  const int sr = lane & 15;
  const int sc = (lane >> 4) * 8;
  const u16* aG0 = Abf + (size_t)(m0 + 16 * wv + sr) * KDIM + sc;   // subtile wv
  const u16* aG1 = aG0 + (size_t)64 * KDIM;                          // subtile wv+4
  int wr0 = n0 + 16 * wv + sr;       if (wr0 >= NCLS) wr0 = NCLS - 1;
  int wr1 = n0 + 64 + 16 * wv + sr;  if (wr1 >= NCLS) wr1 = NCLS - 1;
  const u16* wG0 = Wbf + (size_t)wr0 * KDIM + sc;
  const u16* wG1 = Wbf + (size_t)wr1 * KDIM + sc;

  f32x4 acc[4][4] = {};

  const int wm = (wv & 1) * 64;
  const int wn = (wv >> 1) * 64;
  const int ln = lane & 15;   // MFMA frag: row within 16-row group
  const int kq = lane >> 4;   // k-slice quad
  const int sA = wm >> 4;     // subtile base index for this wave
  const int sW = wn >> 4;

  constexpr int NT = KDIM / BK;   // 16

#define STAGE(BUF, KT)                                   \
  do {                                                   \
    const int _o = (KT) * BK;                            \
    gl16(aG0 + _o, &lA[(BUF)][wv * 512]);                \
    gl16(aG1 + _o, &lA[(BUF)][(4 + wv) * 512]);          \
    gl16(wG0 + _o, &lW[(BUF)][wv * 512]);                \
    gl16(wG1 + _o, &lW[(BUF)][(4 + wv) * 512]);          \
  } while (0)

  // prologue: 2 stages in flight (8 vmem ops/wave)
  STAGE(0, 0);
  STAGE(1, 1);

#pragma unroll
  for (int kt = 0; kt < NT; ++kt) {
    if (kt == NT - 1)
      asm volatile("s_waitcnt vmcnt(0) lgkmcnt(0)" ::: "memory");
    else
      asm volatile("s_waitcnt vmcnt(4) lgkmcnt(0)" ::: "memory");
    __builtin_amdgcn_s_barrier();
    __builtin_amdgcn_sched_barrier(0);

    const int b = kt % 3;   // compile-time (loop fully unrolled)
    s16x8 af[4], wf[4];
#pragma unroll
    for (int i = 0; i < 4; ++i)
      af[i] = *(const s16x8*)&lA[b][(sA + i) * 512 + kq * 128 + ln * 8];
#pragma unroll
    for (int j = 0; j < 4; ++j)
      wf[j] = *(const s16x8*)&lW[b][(sW + j) * 512 + kq * 128 + ln * 8];

    if (kt + 2 < NT) STAGE((kt + 2) % 3, kt + 2);   // lands >= 2 iters later

    __builtin_amdgcn_s_setprio(1);
#pragma unroll
    for (int i = 0; i < 4; ++i)
#pragma unroll
      for (int j = 0; j < 4; ++j)
        acc[i][j] = __builtin_amdgcn_mfma_f32_16x16x32_bf16(af[i], wf[j], acc[i][j], 0, 0, 0);
    __builtin_amdgcn_s_setprio(0);
  }
#undef STAGE

  // epilogue: C/D layout col = lane&15, row = (lane>>4)*4 + reg  [verified m89/m91]
  constexpr float S_ = 30.0f;
  constexpr float COS_M = 0.87758256189037276f;
  constexpr float SIN_M = 0.47942553860420301f;
  constexpr float TH_ = -0.87758256189037276f;       // cos(pi - 0.5)
  constexpr float FALLB = 30.0f * 0.47942553860420301f * 0.5f;  // S*sin(m)*m

#pragma unroll
  for (int i = 0; i < 4; ++i) {
    const int lrow_b = wm + 16 * i + 4 * kq;
#pragma unroll
    for (int j = 0; j < 4; ++j) {
      const int col = wn + 16 * j + ln;
      const int gcol = n0 + col;
      if (gcol < NCLS) {
#pragma unroll
        for (int rg = 0; rg < 4; ++rg) {
          const int lrow = lrow_b + rg;
          const float cosv = acc[i][j][rg];
          float o = S_ * cosv;
          if (gcol == lbl[lrow]) {
            const float s2 = fmaxf(1.0f - cosv * cosv, 0.0f);
            const float sine = sqrtf(s2);
            float phi = cosv * COS_M - sine * SIN_M;
            phi = (cosv > TH_) ? phi : (cosv - FALLB);
            o = S_ * phi;
          }
          out[(size_t)(m0 + lrow) * NCLS + gcol] = o;
        }
      }
    }
  }
}

// ---- Fallback kernel (ws too small for bf16 W): previous proven fused version ----
__global__ __launch_bounds__(256) void arcface_gemm(const u16* __restrict__ Abf,
                                                    const float* __restrict__ W,
                                                    const int* __restrict__ label,
                                                    float* __restrict__ out) {
  __shared__ u16 lA[BM * LDST];
  __shared__ u16 lW[BN * LDST];
  __shared__ float rnw[BN];
  __shared__ int lbl[BM];

  const int tid = threadIdx.x;
  const int m0 = blockIdx.x * BM;
  const int n0 = blockIdx.y * BN;

  if (tid < BM) lbl[tid] = label[m0 + tid];

  const int r = tid >> 1;
  const int half = tid & 1;
  int c = n0 + r;
  if (c >= NCLS) c = NCLS - 1;

  const u16* aptr = Abf + (size_t)(m0 + r) * KDIM + half * 16;
  const float* wptr = W + (size_t)c * KDIM + half * 16;

  uint4 a0 = *(const uint4*)(aptr);
  uint4 a1 = *(const uint4*)(aptr + 8);
  float4 w0 = *(const float4*)(wptr);
  float4 w1 = *(const float4*)(wptr + 4);
  float4 w2 = *(const float4*)(wptr + 8);
  float4 w3 = *(const float4*)(wptr + 12);

  f32x4 acc[4][4] = {};
  float ss = 0.0f;

  const int lane = tid & 63;
  const int wv = tid >> 6;
  const int wm = (wv & 1) * 64;
  const int wn = (wv >> 1) * 64;
  const int ln = lane & 15;
  const int kq = lane >> 4;

  const int aw = r * LDST + half * 16;

  for (int kt = 0; kt < KDIM / BK; ++kt) {
    __syncthreads();
    *(uint4*)&lA[aw] = a0;
    *(uint4*)&lA[aw + 8] = a1;
    ss += w0.x * w0.x + w0.y * w0.y + w0.z * w0.z + w0.w * w0.w;
    ss += w1.x * w1.x + w1.y * w1.y + w1.z * w1.z + w1.w * w1.w;
    ss += w2.x * w2.x + w2.y * w2.y + w2.z * w2.z + w2.w * w2.w;
    ss += w3.x * w3.x + w3.y * w3.y + w3.z * w3.z + w3.w * w3.w;
    uint4 p0, p1;
    p0.x = pk2(w0.x, w0.y); p0.y = pk2(w0.z, w0.w);
    p0.z = pk2(w1.x, w1.y); p0.w = pk2(w1.z, w1.w);
    p1.x = pk2(w2.x, w2.y); p1.y = pk2(w2.z, w2.w);
    p1.z = pk2(w3.x, w3.y); p1.w = pk2(w3.z, w3.w);
    *(uint4*)&lW[aw] = p0;
    *(uint4*)&lW[aw + 8] = p1;
    __syncthreads();

    if (kt < KDIM / BK - 1) {
      const u16* ap = aptr + (kt + 1) * BK;
      a0 = *(const uint4*)(ap);
      a1 = *(const uint4*)(ap + 8);
      const float* wp = wptr + (kt + 1) * BK;
      w0 = *(const float4*)(wp);
      w1 = *(const float4*)(wp + 4);
      w2 = *(const float4*)(wp + 8);
      w3 = *(const float4*)(wp + 12);
    }

    s16x8 af[4], wf[4];
#pragma unroll
    for (int i = 0; i < 4; ++i)
      af[i] = *(const s16x8*)&lA[(wm + 16 * i + ln) * LDST + kq * 8];
#pragma unroll
    for (int j = 0; j < 4; ++j)
      wf[j] = *(const s16x8*)&lW[(wn + 16 * j + ln) * LDST + kq * 8];
#pragma unroll
    for (int i = 0; i < 4; ++i)
#pragma unroll
      for (int j = 0; j < 4; ++j)
        acc[i][j] = __builtin_amdgcn_mfma_f32_16x16x32_bf16(af[i], wf[j], acc[i][j], 0, 0, 0);
  }

  const float sst = ss + __shfl_xor(ss, 1);
  if (half == 0) rnw[r] = 1.0f / fmaxf(sqrtf(sst), 1e-12f);
  __syncthreads();

  constexpr float S_ = 30.0f;
  constexpr float COS_M = 0.87758256189037276f;
  constexpr float SIN_M = 0.47942553860420301f;
  constexpr float TH_ = -0.87758256189037276f;
  constexpr float FALLB = 30.0f * 0.47942553860420301f * 0.5f;

#pragma unroll
  for (int i = 0; i < 4; ++i) {
    const int lrow_b = wm + 16 * i + 4 * kq;
#pragma unroll
    for (int j = 0; j < 4; ++j) {
      const int col = wn + 16 * j + ln;
      const int gcol = n0 + col;
      const float rw = rnw[col];
      if (gcol < NCLS) {
#pragma unroll
        for (int rg = 0; rg < 4; ++rg) {
          const int lrow = lrow_b + rg;
          const float cosv = acc[i][j][rg] * rw;
          float o = S_ * cosv;
          if (gcol == lbl[lrow]) {
            const float s2 = fmaxf(1.0f - cosv * cosv, 0.0f);
            const float sine = sqrtf(s2);
            float phi = cosv * COS_M - sine * SIN_M;
            phi = (cosv > TH_) ? phi : (cosv - FALLB);
            o = S_ * phi;
          }
          out[(size_t)(m0 + lrow) * NCLS + gcol] = o;
        }
      }
    }
  }
}

extern "C" void kernel_launch(void* const* d_in, const int* in_sizes, int n_in,
                              void* d_out, int out_size, void* d_ws, size_t ws_size,
                              hipStream_t stream) {
  const float* input = (const float*)d_in[0];
  const int* label = (const int*)d_in[1];
  const float* weight = (const float*)d_in[2];
  float* out = (float*)d_out;
  u16* abf = (u16*)d_ws;  // 1024*512 bf16 = 1 MB normalized input

  hipLaunchKernelGGL(norm_input_kernel, dim3(MDIM), dim3(256), 0, stream, input, abf);

  const size_t a_bytes = (size_t)MDIM * KDIM * sizeof(u16);
  const size_t w_bytes = (size_t)NCLS * KDIM * sizeof(u16);
  if (ws_size >= a_bytes + w_bytes) {
    u16* wbf = abf + (size_t)MDIM * KDIM;  // 100000*512 bf16 = 102.4 MB
    hipLaunchKernelGGL(norm_weight_kernel, dim3(NCLS / 4), dim3(256), 0, stream, weight, wbf);
    hipLaunchKernelGGL(arcface_gemm_bf16, dim3(NWG), dim3(256), 0, stream, abf, wbf, label, out);
  } else {
    dim3 grid(MDIM / BM, (NCLS + BN - 1) / BN);
    hipLaunchKernelGGL(arcface_gemm, grid, dim3(256), 0, stream, abf, weight, label, out);
  }
}

// Round 6
// 731.601 us; speedup vs baseline: 1.0731x; 1.0684x over previous
//
#include <hip/hip_runtime.h>

// ArcMarginProduct: out[b,c] = S * (c==label[b] ? phi : cos)
//   cos = <input_b/||input_b||, weight_c/||weight_c||>
//   phi = cos*cos(m) - sine*sin(m), fallback cos - S*sin(m)*m if cos <= cos(pi-m)
// B=1024, D=512, C=100000. fp32 in/out; bf16 MFMA inside.
//
// R1/R2: prenorm W to bf16 (FETCH 804->55 MB), XCD swizzle, 286 us gemm.
// R3: gl16 subtiled staging -> bank conflicts 0, but latency-bound (315 us).
// R5: counted-vmcnt triple-buffer pipeline: NEUTRAL (312 us). Occupancy 21%,
//     ~1.7 blocks/CU resident vs 3 possible; per-iter latency exposed, no TLP.
// R6: occupancy push — double-buffer LDS (48.5->33 KB => 4 blocks/CU cap),
//     keep counted vmcnt(4) (no in-loop drains), add cheap reads-done barrier
//     for WAR on the 2-buffer scheme, __launch_bounds__(256,4), epilogue
//     stores reordered row-major for write-combining.

#define MDIM 1024
#define KDIM 512
#define NCLS 100000

#define BM 128
#define BN 128
#define BK 32
#define LDST 40   // fallback kernel only: padded row stride

#define NTILES ((NCLS + BN - 1) / BN)   // 782
#define NWG (8 * NTILES)                // 6256, divisible by 8

typedef unsigned short u16;
typedef unsigned int u32;
typedef short s16x8 __attribute__((ext_vector_type(8)));
typedef float f32x4 __attribute__((ext_vector_type(4)));

// round-to-nearest-even fp32 -> bf16, two values packed into a u32
__device__ __forceinline__ u32 pk2(float a, float b) {
  u32 ua = __builtin_bit_cast(u32, a);
  u32 ub = __builtin_bit_cast(u32, b);
  ua += 0x7FFFu + ((ua >> 16) & 1u);
  ub += 0x7FFFu + ((ub >> 16) & 1u);
  return (ua >> 16) | (ub & 0xFFFF0000u);
}

// async global->LDS, 16 B per lane. LDS dest is wave-uniform base;
// lane l writes base + l*16 B. Global src is per-lane.
__device__ __forceinline__ void gl16(const u16* g, u16* l) {
  __builtin_amdgcn_global_load_lds(
      (const __attribute__((address_space(1))) void*)g,
      (__attribute__((address_space(3))) void*)l, 16, 0, 0);
}

// ---- Kernel 1: L2-normalize input rows, store bf16 row-major [1024][512] ----
__global__ __launch_bounds__(256) void norm_input_kernel(const float* __restrict__ in,
                                                         u16* __restrict__ abf) {
  const int row = blockIdx.x;
  const int tid = threadIdx.x;
  const float2 v = *reinterpret_cast<const float2*>(in + (size_t)row * KDIM + 2 * tid);
  float ss = v.x * v.x + v.y * v.y;
#pragma unroll
  for (int off = 32; off > 0; off >>= 1) ss += __shfl_down(ss, off);
  __shared__ float part[4];
  if ((tid & 63) == 0) part[tid >> 6] = ss;
  __syncthreads();
  const float tot = part[0] + part[1] + part[2] + part[3];
  const float rn = 1.0f / fmaxf(sqrtf(tot), 1e-12f);  // F.normalize: x / max(||x||, eps)
  reinterpret_cast<u32*>(abf)[row * (KDIM / 2) + tid] = pk2(v.x * rn, v.y * rn);
}

// ---- Kernel 1b: L2-normalize weight rows, store bf16 row-major [100000][512] ----
__global__ __launch_bounds__(256) void norm_weight_kernel(const float* __restrict__ W,
                                                          u16* __restrict__ wbf) {
  const int row = blockIdx.x * 4 + (threadIdx.x >> 6);
  const int lane = threadIdx.x & 63;
  const float* p = W + (size_t)row * KDIM + lane * 8;
  const float4 v0 = *reinterpret_cast<const float4*>(p);
  const float4 v1 = *reinterpret_cast<const float4*>(p + 4);
  float ss = v0.x * v0.x + v0.y * v0.y + v0.z * v0.z + v0.w * v0.w
           + v1.x * v1.x + v1.y * v1.y + v1.z * v1.z + v1.w * v1.w;
#pragma unroll
  for (int off = 32; off > 0; off >>= 1) ss += __shfl_xor(ss, off);
  const float rn = 1.0f / fmaxf(sqrtf(ss), 1e-12f);
  uint4 o;
  o.x = pk2(v0.x * rn, v0.y * rn);
  o.y = pk2(v0.z * rn, v0.w * rn);
  o.z = pk2(v1.x * rn, v1.y * rn);
  o.w = pk2(v1.z * rn, v1.w * rn);
  *reinterpret_cast<uint4*>(wbf + (size_t)row * KDIM + lane * 8) = o;
}

// ---- Kernel 2 (main): C = Anorm * Wnorm^T, both bf16, fused ArcFace epilogue ----
// 128x128 tile, 256 threads = 4 waves 2x2, each wave 64x64 via 4x4 of 16x16x32 MFMA.
// LDS: DOUBLE buffer of [16-row x 32-k subtile]=1KB granules (conflict-free, R3),
// total 33 KB -> 4 blocks/CU. Per iter:
//   wait vmcnt(4)  [stage kt landed; stage kt+1 stays in flight]
//   barrier1; ds_read frags; lgkmcnt(0); barrier2 (reads done)
//   STAGE(kt+2) overwrites just-read buf[kt&1]; MFMA.
//   RAW: top wait retires exactly stage kt.  WAR: barrier2 precedes overwrite.
__global__ __launch_bounds__(256, 4) void arcface_gemm_bf16(const u16* __restrict__ Abf,
                                                            const u16* __restrict__ Wbf,
                                                            const int* __restrict__ label,
                                                            float* __restrict__ out) {
  __shared__ u16 lA[2][BM * BK];   // 2 x 8 KB
  __shared__ u16 lW[2][BN * BK];   // 2 x 8 KB
  __shared__ int lbl[BM];

  const int tid = threadIdx.x;
  const int orig = blockIdx.x;
  const int wg = (orig & 7) * NTILES + (orig >> 3);
  const int m0 = (wg & 7) * BM;
  const int n0 = (wg >> 3) * BN;

  if (tid < BM) lbl[tid] = label[m0 + tid];

  const int lane = tid & 63;
  const int wv = tid >> 6;

  // staging source: lane l -> (row in subtile = l&15, 16B k-slice = l>>4)
  const int sr = lane & 15;
  const int sc = (lane >> 4) * 8;
  const u16* aG0 = Abf + (size_t)(m0 + 16 * wv + sr) * KDIM + sc;   // subtile wv
  const u16* aG1 = aG0 + (size_t)64 * KDIM;                          // subtile wv+4
  int wr0 = n0 + 16 * wv + sr;       if (wr0 >= NCLS) wr0 = NCLS - 1;
  int wr1 = n0 + 64 + 16 * wv + sr;  if (wr1 >= NCLS) wr1 = NCLS - 1;
  const u16* wG0 = Wbf + (size_t)wr0 * KDIM + sc;
  const u16* wG1 = Wbf + (size_t)wr1 * KDIM + sc;

  f32x4 acc[4][4] = {};

  const int wm = (wv & 1) * 64;
  const int wn = (wv >> 1) * 64;
  const int ln = lane & 15;   // MFMA frag: row within 16-row group
  const int kq = lane >> 4;   // k-slice quad
  const int sA = wm >> 4;     // subtile base index for this wave
  const int sW = wn >> 4;

  constexpr int NT = KDIM / BK;   // 16

#define STAGE(BUF, KT)                                   \
  do {                                                   \
    const int _o = (KT) * BK;                            \
    gl16(aG0 + _o, &lA[(BUF)][wv * 512]);                \
    gl16(aG1 + _o, &lA[(BUF)][(4 + wv) * 512]);          \
    gl16(wG0 + _o, &lW[(BUF)][wv * 512]);                \
    gl16(wG1 + _o, &lW[(BUF)][(4 + wv) * 512]);          \
  } while (0)

  // prologue: 2 stages in flight (8 vmem ops/wave)
  STAGE(0, 0);
  STAGE(1, 1);

#pragma unroll
  for (int kt = 0; kt < NT; ++kt) {
    if (kt == NT - 1)
      asm volatile("s_waitcnt vmcnt(0)" ::: "memory");
    else
      asm volatile("s_waitcnt vmcnt(4)" ::: "memory");   // stage kt done; kt+1 in flight
    __builtin_amdgcn_s_barrier();                        // buf[kt&1] visible to all
    __builtin_amdgcn_sched_barrier(0);

    const int b = kt & 1;   // compile-time (loop fully unrolled)
    s16x8 af[4], wf[4];
#pragma unroll
    for (int i = 0; i < 4; ++i)
      af[i] = *(const s16x8*)&lA[b][(sA + i) * 512 + kq * 128 + ln * 8];
#pragma unroll
    for (int j = 0; j < 4; ++j)
      wf[j] = *(const s16x8*)&lW[b][(sW + j) * 512 + kq * 128 + ln * 8];

    asm volatile("s_waitcnt lgkmcnt(0)" ::: "memory");   // my frag reads in regs
    __builtin_amdgcn_sched_barrier(0);
    __builtin_amdgcn_s_barrier();                        // ALL waves' reads done

    if (kt + 2 < NT) STAGE(kt & 1, kt + 2);   // overwrite just-read buffer

    __builtin_amdgcn_s_setprio(1);
#pragma unroll
    for (int i = 0; i < 4; ++i)
#pragma unroll
      for (int j = 0; j < 4; ++j)
        acc[i][j] = __builtin_amdgcn_mfma_f32_16x16x32_bf16(af[i], wf[j], acc[i][j], 0, 0, 0);
    __builtin_amdgcn_s_setprio(0);
  }
#undef STAGE

  // epilogue: C/D layout col = lane&15, row = (lane>>4)*4 + reg  [verified m89/m91]
  // loop order: row-major (i, rg outer; j inner) -> 4 stores land in one
  // 256B-aligned row segment (cols n0+wn+ln, +16, +32, +48) for write-combining.
  constexpr float S_ = 30.0f;
  constexpr float COS_M = 0.87758256189037276f;
  constexpr float SIN_M = 0.47942553860420301f;
  constexpr float TH_ = -0.87758256189037276f;       // cos(pi - 0.5)
  constexpr float FALLB = 30.0f * 0.47942553860420301f * 0.5f;  // S*sin(m)*m

#pragma unroll
  for (int i = 0; i < 4; ++i) {
#pragma unroll
    for (int rg = 0; rg < 4; ++rg) {
      const int lrow = wm + 16 * i + 4 * kq + rg;
      const int row_lbl = lbl[lrow];
      float* const orow = out + (size_t)(m0 + lrow) * NCLS;
#pragma unroll
      for (int j = 0; j < 4; ++j) {
        const int gcol = n0 + wn + 16 * j + ln;
        if (gcol < NCLS) {
          const float cosv = acc[i][j][rg];
          float o = S_ * cosv;
          if (gcol == row_lbl) {
            const float s2 = fmaxf(1.0f - cosv * cosv, 0.0f);
            const float sine = sqrtf(s2);
            float phi = cosv * COS_M - sine * SIN_M;
            phi = (cosv > TH_) ? phi : (cosv - FALLB);
            o = S_ * phi;
          }
          orow[gcol] = o;
        }
      }
    }
  }
}

// ---- Fallback kernel (ws too small for bf16 W): previous proven fused version ----
__global__ __launch_bounds__(256) void arcface_gemm(const u16* __restrict__ Abf,
                                                    const float* __restrict__ W,
                                                    const int* __restrict__ label,
                                                    float* __restrict__ out) {
  __shared__ u16 lA[BM * LDST];
  __shared__ u16 lW[BN * LDST];
  __shared__ float rnw[BN];
  __shared__ int lbl[BM];

  const int tid = threadIdx.x;
  const int m0 = blockIdx.x * BM;
  const int n0 = blockIdx.y * BN;

  if (tid < BM) lbl[tid] = label[m0 + tid];

  const int r = tid >> 1;
  const int half = tid & 1;
  int c = n0 + r;
  if (c >= NCLS) c = NCLS - 1;

  const u16* aptr = Abf + (size_t)(m0 + r) * KDIM + half * 16;
  const float* wptr = W + (size_t)c * KDIM + half * 16;

  uint4 a0 = *(const uint4*)(aptr);
  uint4 a1 = *(const uint4*)(aptr + 8);
  float4 w0 = *(const float4*)(wptr);
  float4 w1 = *(const float4*)(wptr + 4);
  float4 w2 = *(const float4*)(wptr + 8);
  float4 w3 = *(const float4*)(wptr + 12);

  f32x4 acc[4][4] = {};
  float ss = 0.0f;

  const int lane = tid & 63;
  const int wv = tid >> 6;
  const int wm = (wv & 1) * 64;
  const int wn = (wv >> 1) * 64;
  const int ln = lane & 15;
  const int kq = lane >> 4;

  const int aw = r * LDST + half * 16;

  for (int kt = 0; kt < KDIM / BK; ++kt) {
    __syncthreads();
    *(uint4*)&lA[aw] = a0;
    *(uint4*)&lA[aw + 8] = a1;
    ss += w0.x * w0.x + w0.y * w0.y + w0.z * w0.z + w0.w * w0.w;
    ss += w1.x * w1.x + w1.y * w1.y + w1.z * w1.z + w1.w * w1.w;
    ss += w2.x * w2.x + w2.y * w2.y + w2.z * w2.z + w2.w * w2.w;
    ss += w3.x * w3.x + w3.y * w3.y + w3.z * w3.z + w3.w * w3.w;
    uint4 p0, p1;
    p0.x = pk2(w0.x, w0.y); p0.y = pk2(w0.z, w0.w);
    p0.z = pk2(w1.x, w1.y); p0.w = pk2(w1.z, w1.w);
    p1.x = pk2(w2.x, w2.y); p1.y = pk2(w2.z, w2.w);
    p1.z = pk2(w3.x, w3.y); p1.w = pk2(w3.z, w3.w);
    *(uint4*)&lW[aw] = p0;
    *(uint4*)&lW[aw + 8] = p1;
    __syncthreads();

    if (kt < KDIM / BK - 1) {
      const u16* ap = aptr + (kt + 1) * BK;
      a0 = *(const uint4*)(ap);
      a1 = *(const uint4*)(ap + 8);
      const float* wp = wptr + (kt + 1) * BK;
      w0 = *(const float4*)(wp);
      w1 = *(const float4*)(wp + 4);
      w2 = *(const float4*)(wp + 8);
      w3 = *(const float4*)(wp + 12);
    }

    s16x8 af[4], wf[4];
#pragma unroll
    for (int i = 0; i < 4; ++i)
      af[i] = *(const s16x8*)&lA[(wm + 16 * i + ln) * LDST + kq * 8];
#pragma unroll
    for (int j = 0; j < 4; ++j)
      wf[j] = *(const s16x8*)&lW[(wn + 16 * j + ln) * LDST + kq * 8];
#pragma unroll
    for (int i = 0; i < 4; ++i)
#pragma unroll
      for (int j = 0; j < 4; ++j)
        acc[i][j] = __builtin_amdgcn_mfma_f32_16x16x32_bf16(af[i], wf[j], acc[i][j], 0, 0, 0);
  }

  const float sst = ss + __shfl_xor(ss, 1);
  if (half == 0) rnw[r] = 1.0f / fmaxf(sqrtf(sst), 1e-12f);
  __syncthreads();

  constexpr float S_ = 30.0f;
  constexpr float COS_M = 0.87758256189037276f;
  constexpr float SIN_M = 0.47942553860420301f;
  constexpr float TH_ = -0.87758256189037276f;
  constexpr float FALLB = 30.0f * 0.47942553860420301f * 0.5f;

#pragma unroll
  for (int i = 0; i < 4; ++i) {
    const int lrow_b = wm + 16 * i + 4 * kq;
#pragma unroll
    for (int j = 0; j < 4; ++j) {
      const int col = wn + 16 * j + ln;
      const int gcol = n0 + col;
      const float rw = rnw[col];
      if (gcol < NCLS) {
#pragma unroll
        for (int rg = 0; rg < 4; ++rg) {
          const int lrow = lrow_b + rg;
          const float cosv = acc[i][j][rg] * rw;
          float o = S_ * cosv;
          if (gcol == lbl[lrow]) {
            const float s2 = fmaxf(1.0f - cosv * cosv, 0.0f);
            const float sine = sqrtf(s2);
            float phi = cosv * COS_M - sine * SIN_M;
            phi = (cosv > TH_) ? phi : (cosv - FALLB);
            o = S_ * phi;
          }
          out[(size_t)(m0 + lrow) * NCLS + gcol] = o;
        }
      }
    }
  }
}

extern "C" void kernel_launch(void* const* d_in, const int* in_sizes, int n_in,
                              void* d_out, int out_size, void* d_ws, size_t ws_size,
                              hipStream_t stream) {
  const float* input = (const float*)d_in[0];
  const int* label = (const int*)d_in[1];
  const float* weight = (const float*)d_in[2];
  float* out = (float*)d_out;
  u16* abf = (u16*)d_ws;  // 1024*512 bf16 = 1 MB normalized input

  hipLaunchKernelGGL(norm_input_kernel, dim3(MDIM), dim3(256), 0, stream, input, abf);

  const size_t a_bytes = (size_t)MDIM * KDIM * sizeof(u16);
  const size_t w_bytes = (size_t)NCLS * KDIM * sizeof(u16);
  if (ws_size >= a_bytes + w_bytes) {
    u16* wbf = abf + (size_t)MDIM * KDIM;  // 100000*512 bf16 = 102.4 MB
    hipLaunchKernelGGL(norm_weight_kernel, dim3(NCLS / 4), dim3(256), 0, stream, weight, wbf);
    hipLaunchKernelGGL(arcface_gemm_bf16, dim3(NWG), dim3(256), 0, stream, abf, wbf, label, out);
  } else {
    dim3 grid(MDIM / BM, (NCLS + BN - 1) / BN);
    hipLaunchKernelGGL(arcface_gemm, grid, dim3(256), 0, stream, abf, weight, label, out);
  }
}